// Round 13
// baseline (231.314 us; speedup 1.0000x reference)
//
#include <hip/hip_runtime.h>
#include <hip/hip_bf16.h>

typedef __attribute__((ext_vector_type(8))) short bf16x8;
typedef __attribute__((ext_vector_type(4))) float fvec4;
typedef __attribute__((ext_vector_type(16))) float f32x16;
typedef __attribute__((ext_vector_type(8))) unsigned short u16x8;

// B=4, T=256, U=64 -> M = 65536 rows; K(J)=512; N(V)=1024

__device__ __forceinline__ unsigned short f2bf(float f) {
  unsigned int u = __builtin_bit_cast(unsigned int, f);
  u += 0x7FFFu + ((u >> 16) & 1u);   // round-to-nearest-even
  return (unsigned short)(u >> 16);
}

__device__ __forceinline__ float fast_tanh(float x) {
  float cx = fminf(fmaxf(x, -9.0f), 9.0f);
  float e2 = __expf(cx + cx);
  return (e2 - 1.0f) * __builtin_amdgcn_rcpf(e2 + 1.0f);
}

// ---- fused prep: enc-proj (blocks 0..127), pred-proj (128..159), W_out^T (160..287)

__device__ __forceinline__ void proj_body(
    const float* __restrict__ x, const float* __restrict__ W,
    const float* __restrict__ bias, float* __restrict__ out,
    int blk, uint8_t* sh) {
  float (*xt)[9] = (float (*)[9])sh;   // [256][9] f32 = 9216 B
  const int tid = threadIdx.x;
  const int row0 = blk << 3;
  #pragma unroll
  for (int i = 0; i < 8; ++i)
    xt[tid][i] = x[(size_t)(row0 + i) * 256 + tid];
  __syncthreads();
  float acc0[8] = {0.f,0.f,0.f,0.f,0.f,0.f,0.f,0.f};
  float acc1[8] = {0.f,0.f,0.f,0.f,0.f,0.f,0.f,0.f};
  #pragma unroll 4
  for (int k = 0; k < 256; ++k) {
    float w0 = W[(size_t)k * 512 + tid];
    float w1 = W[(size_t)k * 512 + tid + 256];
    #pragma unroll
    for (int r = 0; r < 8; ++r) {
      float xv = xt[k][r];
      acc0[r] = fmaf(xv, w0, acc0[r]);
      acc1[r] = fmaf(xv, w1, acc1[r]);
    }
  }
  float b0 = bias[tid], b1 = bias[tid + 256];
  #pragma unroll
  for (int r = 0; r < 8; ++r) {
    out[(size_t)(row0 + r) * 512 + tid]       = acc0[r] + b0;
    out[(size_t)(row0 + r) * 512 + tid + 256] = acc1[r] + b1;
  }
}

// W_out [512 k][1024 n] f32 -> Bt3 K16-sliced bf16:
//   dst = (n>>9)<<18 | (k>>4)<<13 | (n&511)<<4 | (k&15)
// -> one 32x32x16 B-frag (32 n-rows x 8 k halves) = ONE contiguous 1 KiB segment.
__device__ __forceinline__ void transpose_body(
    const float* __restrict__ W, unsigned short* __restrict__ Bt3,
    int blk, uint8_t* sh) {
  unsigned short (*tile)[65] = (unsigned short (*)[65])sh;  // [64 k][65 n]
  const int k0 = (blk & 7) << 6;
  const int n0 = (blk >> 3) << 6;
  const int tid = threadIdx.x;
  #pragma unroll
  for (int i = 0; i < 16; ++i) {
    int idx = tid + (i << 8);
    int r = idx >> 6, c = idx & 63;        // r = k-off, c = n-off (coalesced read)
    tile[r][c] = f2bf(W[(size_t)(k0 + r) * 1024 + n0 + c]);
  }
  __syncthreads();
  #pragma unroll
  for (int i = 0; i < 16; ++i) {
    int idx = tid + (i << 8);
    int r = idx >> 6, c = idx & 63;        // r = n-off, c = k-off
    int ng = n0 + r, kg = k0 + c;
    size_t dst = ((size_t)(ng >> 9) << 18) + ((size_t)(kg >> 4) << 13)
               + ((ng & 511) << 4) + (kg & 15);
    Bt3[dst] = tile[c][r];
  }
}

__global__ __launch_bounds__(256) void prep_kernel(
    const float* __restrict__ enc, const float* __restrict__ We,
    const float* __restrict__ be, float* __restrict__ encp,
    const float* __restrict__ pred, const float* __restrict__ Wd,
    const float* __restrict__ bd, float* __restrict__ predp,
    const float* __restrict__ Wo, unsigned short* __restrict__ Bt3) {
  __shared__ uint8_t sh[9216];
  const int b = blockIdx.x;
  if (b < 128)       proj_body(enc, We, be, encp, b, sh);
  else if (b < 160)  proj_body(pred, Wd, bd, predp, b - 128, sh);
  else               transpose_body(Wo, Bt3, b - 160, sh);
}

// ---- fused joint+gemm, round 13: OCCUPANCY 2x via small per-wave tiles.
// Per-wave output 32x32 (ONE mfma_f32_32x32x16 per K16-step) -> acc = 16 AGPR;
// launch_bounds(512,8) targets <=64 total regs -> 32 waves/CU (vs 16 in r10/r12,
// which were capped by acc64+frags = 128 regs).  Same skeleton otherwise:
// barrier-free K-loop, B direct-to-reg from K16-sliced Bt3 (1 KiB contiguous
// per load), reg ping-pong depth 1.
// Block: 8 waves (2m x 4n) -> tile 64x128.  A = [64][256] bf16 half-tiles
// (32 KiB), K-split with ONE mid-loop rebuild (tanh total unchanged; 4
// drifting blocks/CU overlap the rebuild, unlike r9's 1-block lockstep).
// LDS 34 KiB/block -> 4 blocks/CU.  Epilogue overlay [64][133] f32, raw lgkm
// barriers, 512B-contiguous nontemporal stores.
__global__ __launch_bounds__(512, 8) void fused_gemm(
    const float* __restrict__ encp, const float* __restrict__ predp,
    const unsigned short* __restrict__ Bt3, const float* __restrict__ bout,
    float* __restrict__ out) {
  __shared__ uint8_t lds[34816];   // A-half [64][256]bf16 swz (32K); epi [64][133] f32 (34048)
  const int tid = threadIdx.x;
  const int lane = tid & 63, wid = tid >> 6;
  const int l31 = lane & 31, hi = lane >> 5;
  const int wm = wid >> 2, wn = wid & 3;      // 2m x 4n waves of 32x32
  const int b = blockIdx.x;
  const int wg = ((b & 7) << 10) + (b >> 3);  // XCD swizzle, 8192 % 8 == 0 (bijective)
  const int mt = wg >> 3, nt = wg & 7;        // nt inner: XCD reuses A rows
  const int m0 = mt << 6;
  const int n0 = nt << 7;
  const int half = nt >> 2;

  // per-lane B base: n = n0 + wn*32 + l31; elem = (half<<18)+(kt<<13)+((n&511)<<4)+(hi<<3)
  const unsigned short* Bgl =
      Bt3 + ((size_t)half << 18) + ((((nt & 3) << 7) + (wn << 5) + l31) << 4) + (hi << 3);

  bf16x8 bA, bB;
  bA = *(const bf16x8*)(Bgl);   // kt=0 issued before tanh phase

  // ---- A half-tile build: [64 rows][256 k] bf16, chunk ^= (row&15) swizzle.
  // thread: r = tid>>3, cb = tid&7; 4 chunks (of 32) per thread.
  auto build_A = [&](int h) {
    const int r = tid >> 3, cb = tid & 7;
    const float* erow = encp + ((size_t)mt << 9) + (h << 8);
    const float* prow = predp + ((size_t)(((mt >> 8) << 6) + r) << 9) + (h << 8);
    uint8_t* rowbase = lds + (r << 9);
    #pragma unroll
    for (int c8 = 0; c8 < 4; ++c8) {
      int chunk = cb + (c8 << 3);
      int k8 = chunk << 3;
      fvec4 e0 = *(const fvec4*)(erow + k8);
      fvec4 e1 = *(const fvec4*)(erow + k8 + 4);
      fvec4 p0 = *(const fvec4*)(prow + k8);
      fvec4 p1 = *(const fvec4*)(prow + k8 + 4);
      u16x8 o;
      #pragma unroll
      for (int i = 0; i < 4; ++i) o[i]     = f2bf(fast_tanh(e0[i] + p0[i]));
      #pragma unroll
      for (int i = 0; i < 4; ++i) o[i + 4] = f2bf(fast_tanh(e1[i] + p1[i]));
      *(u16x8*)(rowbase + ((chunk ^ (r & 15)) << 4)) = o;
    }
  };

  build_A(0);
  asm volatile("s_waitcnt lgkmcnt(0)" ::: "memory");
  __builtin_amdgcn_s_barrier();

  f32x16 acc;
  #pragma unroll
  for (int e = 0; e < 16; ++e) acc[e] = 0.f;

  // A frag: row = wm*32 + l31 (512B stride); chunk = (ktl<<1)|hi, swz ^ (row&15)
  const int arow = (wm << 5) + l31;
  const int abase = arow << 9;
  const int am = arow & 15;

  // one K16-step: prefetch B(kt+1), read 1 A frag, 1 MFMA on cur
  auto step = [&](int kt, bf16x8& cur, bf16x8& nxt) {
    const int ktn = kt < 31 ? kt + 1 : 31;   // last iter: harmless dup reload
    nxt = *(const bf16x8*)(Bgl + (ktn << 13));
    const int ktl = kt & 15;
    bf16x8 af = *(const bf16x8*)(lds + abase + ((((ktl << 1) | hi) ^ am) << 4));
    acc = __builtin_amdgcn_mfma_f32_32x32x16_bf16(cur, af, acc, 0, 0, 0);
  };

  #pragma unroll
  for (int kt = 0; kt < 16; kt += 2) {   // K-half 0; static ping-pong (rule #20)
    step(kt,     bA, bB);
    step(kt + 1, bB, bA);
  }
  // rebuild A for K-half 1 (B(16) already in flight into bA)
  asm volatile("s_waitcnt lgkmcnt(0)" ::: "memory");
  __builtin_amdgcn_s_barrier();          // all waves' half-0 ds_reads done
  build_A(1);
  asm volatile("s_waitcnt lgkmcnt(0)" ::: "memory");
  __builtin_amdgcn_s_barrier();          // half-1 published
  #pragma unroll
  for (int kt = 16; kt < 32; kt += 2) {  // K-half 1 (16 even -> bA is cur)
    step(kt,     bA, bB);
    step(kt + 1, bB, bA);
  }

  // ---- epilogue: overlay epi[64][133] f32 on dead A; raw lgkm barriers only.
  // C mapping (swapped operands): m = l31, n = (reg&3) + 4*hi + 8*(reg>>2).
  float (*epi)[133] = (float (*)[133])lds;
  asm volatile("s_waitcnt lgkmcnt(0)" ::: "memory");
  __builtin_amdgcn_s_barrier();          // K-loop A reads done everywhere
  #pragma unroll
  for (int q = 0; q < 4; ++q) {
    const int col = (wn << 5) + (q << 3) + (hi << 2);
    fvec4 bv = *(const fvec4*)&bout[n0 + col];
    fvec4 o;
    #pragma unroll
    for (int j = 0; j < 4; ++j) o[j] = acc[(q << 2) + j] + bv[j];
    *(fvec4*)&epi[(wm << 5) + l31][col] = o;
  }
  asm volatile("s_waitcnt lgkmcnt(0)" ::: "memory");
  __builtin_amdgcn_s_barrier();          // deposits visible
  #pragma unroll
  for (int j = 0; j < 4; ++j) {
    const int row = (wid << 3) + (j << 1) + hi;   // 8 rows per wave, 2 per instr
    fvec4 v = *(const fvec4*)&epi[row][l31 << 2];
    __builtin_nontemporal_store(
        v, (fvec4*)&out[(size_t)(m0 + row) * 1024 + n0 + (l31 << 2)]);
  }
}

extern "C" void kernel_launch(void* const* d_in, const int* in_sizes, int n_in,
                              void* d_out, int out_size, void* d_ws, size_t ws_size,
                              hipStream_t stream) {
  const float* enc   = (const float*)d_in[0];
  const float* pred  = (const float*)d_in[1];
  const float* W_enc = (const float*)d_in[2];
  const float* b_enc = (const float*)d_in[3];
  const float* W_dec = (const float*)d_in[4];
  const float* b_dec = (const float*)d_in[5];
  const float* W_out = (const float*)d_in[6];
  const float* b_out = (const float*)d_in[7];
  float* out = (float*)d_out;

  uint8_t* ws = (uint8_t*)d_ws;
  float* encp  = (float*)ws;                           // [1024][512] f32, 2 MiB
  float* predp = (float*)(ws + 2097152);               // [256][512]  f32, 0.5 MiB
  unsigned short* bt3 = (unsigned short*)(ws + 2621440);// K16-sliced W_out^T bf16, 1 MiB

  prep_kernel<<<288, 256, 0, stream>>>(enc, W_enc, b_enc, encp,
                                       pred, W_dec, b_dec, predp,
                                       W_out, bt3);
  fused_gemm<<<8192, 512, 0, stream>>>(encp, predp, bt3, b_out, out);
}

// Round 14
// 149.929 us; speedup vs baseline: 1.5428x; 1.5428x over previous
//
#include <hip/hip_runtime.h>
#include <hip/hip_bf16.h>

typedef __attribute__((ext_vector_type(8))) short bf16x8;
typedef __attribute__((ext_vector_type(4))) float fvec4;
typedef __attribute__((ext_vector_type(16))) float f32x16;
typedef __attribute__((ext_vector_type(8))) unsigned short u16x8;

// B=4, T=256, U=64 -> M = 65536 rows; K(J)=512; N(V)=1024

__device__ __forceinline__ unsigned short f2bf(float f) {
  unsigned int u = __builtin_bit_cast(unsigned int, f);
  u += 0x7FFFu + ((u >> 16) & 1u);   // round-to-nearest-even
  return (unsigned short)(u >> 16);
}

__device__ __forceinline__ float fast_tanh(float x) {
  float cx = fminf(fmaxf(x, -9.0f), 9.0f);
  float e2 = __expf(cx + cx);
  return (e2 - 1.0f) * __builtin_amdgcn_rcpf(e2 + 1.0f);
}

// ---- fused prep: enc-proj (blocks 0..127), pred-proj (128..159), W_out^T (160..287)

__device__ __forceinline__ void proj_body(
    const float* __restrict__ x, const float* __restrict__ W,
    const float* __restrict__ bias, float* __restrict__ out,
    int blk, uint8_t* sh) {
  float (*xt)[9] = (float (*)[9])sh;   // [256][9] f32 = 9216 B
  const int tid = threadIdx.x;
  const int row0 = blk << 3;
  #pragma unroll
  for (int i = 0; i < 8; ++i)
    xt[tid][i] = x[(size_t)(row0 + i) * 256 + tid];
  __syncthreads();
  float acc0[8] = {0.f,0.f,0.f,0.f,0.f,0.f,0.f,0.f};
  float acc1[8] = {0.f,0.f,0.f,0.f,0.f,0.f,0.f,0.f};
  #pragma unroll 4
  for (int k = 0; k < 256; ++k) {
    float w0 = W[(size_t)k * 512 + tid];
    float w1 = W[(size_t)k * 512 + tid + 256];
    #pragma unroll
    for (int r = 0; r < 8; ++r) {
      float xv = xt[k][r];
      acc0[r] = fmaf(xv, w0, acc0[r]);
      acc1[r] = fmaf(xv, w1, acc1[r]);
    }
  }
  float b0 = bias[tid], b1 = bias[tid + 256];
  #pragma unroll
  for (int r = 0; r < 8; ++r) {
    out[(size_t)(row0 + r) * 512 + tid]       = acc0[r] + b0;
    out[(size_t)(row0 + r) * 512 + tid + 256] = acc1[r] + b1;
  }
}

// W_out [512 k][1024 n] f32 -> Bt3 K16-sliced bf16:
//   dst = (n>>9)<<18 | (k>>4)<<13 | (n&511)<<4 | (k&15)
// -> one 32x32x16 B-frag (32 n-rows x 8 k halves) = ONE contiguous 1 KiB segment.
__device__ __forceinline__ void transpose_body(
    const float* __restrict__ W, unsigned short* __restrict__ Bt3,
    int blk, uint8_t* sh) {
  unsigned short (*tile)[65] = (unsigned short (*)[65])sh;  // [64 k][65 n]
  const int k0 = (blk & 7) << 6;
  const int n0 = (blk >> 3) << 6;
  const int tid = threadIdx.x;
  #pragma unroll
  for (int i = 0; i < 16; ++i) {
    int idx = tid + (i << 8);
    int r = idx >> 6, c = idx & 63;        // r = k-off, c = n-off (coalesced read)
    tile[r][c] = f2bf(W[(size_t)(k0 + r) * 1024 + n0 + c]);
  }
  __syncthreads();
  #pragma unroll
  for (int i = 0; i < 16; ++i) {
    int idx = tid + (i << 8);
    int r = idx >> 6, c = idx & 63;        // r = n-off, c = k-off
    int ng = n0 + r, kg = k0 + c;
    size_t dst = ((size_t)(ng >> 9) << 18) + ((size_t)(kg >> 4) << 13)
               + ((ng & 511) << 4) + (kg & 15);
    Bt3[dst] = tile[c][r];
  }
}

__global__ __launch_bounds__(256) void prep_kernel(
    const float* __restrict__ enc, const float* __restrict__ We,
    const float* __restrict__ be, float* __restrict__ encp,
    const float* __restrict__ pred, const float* __restrict__ Wd,
    const float* __restrict__ bd, float* __restrict__ predp,
    const float* __restrict__ Wo, unsigned short* __restrict__ Bt3) {
  __shared__ uint8_t sh[9216];
  const int b = blockIdx.x;
  if (b < 128)       proj_body(enc, We, be, encp, b, sh);
  else if (b < 160)  proj_body(pred, Wd, bd, predp, b - 128, sh);
  else               transpose_body(Wo, Bt3, b - 160, sh);
}

// ---- joint: Aj = bf16(tanh(encp+predp)) ONCE (1x tanh, r13 lesson: fused
// tanh redundancy scales with N/BN and binds VALU).  K16-sliced 32-row-panel
// layout mirroring Bt3:  dst = (m>>5)*16384 + (k>>4)*512 + (m&31)*16 + (k&15)
// -> one 32x32x16 A-frag (32 m-rows x 16 k) = ONE contiguous 1 KiB segment.
// Thread: 16 k of one row -> writes 32 B contiguous; 32 lanes = 1 KiB segment.
__global__ __launch_bounds__(256) void joint_kernel(
    const float* __restrict__ encp, const float* __restrict__ predp,
    unsigned short* __restrict__ Aj) {
  const int vid = blockIdx.x * 256 + threadIdx.x;   // 2M threads
  const int r = vid & 31;         // row within 32-panel
  const int s = vid >> 5;
  const int kt = s & 31;          // K16 slice
  const int g = s >> 5;           // 32-row panel 0..2047
  const int k0 = kt << 4;
  // m = g*32 + r:  enc row = m>>6 = g>>1 (lane-uniform);
  // pred row = (m>>14)*64 + (m&63) = (g>>9)*64 + (g&1)*32 + r
  const float* e = encp + ((size_t)(g >> 1) << 9) + k0;
  const float* p = predp + (((size_t)((g >> 9) << 6) + ((g & 1) << 5) + r) << 9) + k0;
  fvec4 ev0 = *(const fvec4*)e,        ev1 = *(const fvec4*)(e + 4);
  fvec4 ev2 = *(const fvec4*)(e + 8),  ev3 = *(const fvec4*)(e + 12);
  fvec4 pv0 = *(const fvec4*)p,        pv1 = *(const fvec4*)(p + 4);
  fvec4 pv2 = *(const fvec4*)(p + 8),  pv3 = *(const fvec4*)(p + 12);
  u16x8 o0, o1;
  #pragma unroll
  for (int i = 0; i < 4; ++i) {
    o0[i]     = f2bf(fast_tanh(ev0[i] + pv0[i]));
    o0[i + 4] = f2bf(fast_tanh(ev1[i] + pv1[i]));
    o1[i]     = f2bf(fast_tanh(ev2[i] + pv2[i]));
    o1[i + 4] = f2bf(fast_tanh(ev3[i] + pv3[i]));
  }
  unsigned short* dst = Aj + ((size_t)g << 14) + (kt << 9) + (r << 4);
  *(u16x8*)dst = o0;
  *(u16x8*)(dst + 8) = o1;
}

// ---- gemm: BM=64, BN=512, 8 waves x (64M x 64N via 2x2 32x32x16 frags).
// BOTH operands direct global->reg as contiguous 1 KiB frag loads (Aj + Bt3
// K16-sliced layouts); register ping-pong depth 1 on each.  NO LDS staging,
// NO tanh, ZERO barriers before the epilogue -- waves fully independent
// (removes r10's tanh-VALU ~17us and LDS-A-port ~20us from the critical sum).
// acc 64 AGPR + frag dbuf 32 VGPR -> 2 blocks/CU (16 waves).
// Epilogue: r12's verified LDS re-layout, raw lgkm barriers, nontemporal
// contiguous 1 KiB stores.
__global__ __launch_bounds__(512, 4) void gemm_kernel(
    const unsigned short* __restrict__ Aj, const unsigned short* __restrict__ Bt3,
    const float* __restrict__ bout, float* __restrict__ out) {
  __shared__ uint8_t lds[66048];   // epi: [32][516] f32
  const int tid = threadIdx.x;
  const int lane = tid & 63, wid = tid >> 6;
  const int l31 = lane & 31, hi = lane >> 5;
  const int b = blockIdx.x;
  const int wg = ((b & 7) << 8) + (b >> 3);   // XCD swizzle, 2048 % 8 == 0 (bijective)
  const int mt = wg >> 1, half = wg & 1;      // half inner: pair shares Aj panel (L2 hit)
  const int m0 = mt << 6;
  const int cb0 = half << 9;

  // B frag (na, kt): contiguous 1 KiB at Bgl + kt*8192 + na*512 elems
  const unsigned short* Bgl =
      Bt3 + ((size_t)half << 18) + (((wid << 6) + l31) << 4) + (hi << 3);
  // A frag (ma, kt): group g = mt*2 + ma; contiguous 1 KiB at
  // Agl + ma*16384 + kt*512 elems
  const unsigned short* Agl =
      Aj + ((size_t)mt << 15) + (l31 << 4) + (hi << 3);

  bf16x8 bA[2], bB[2], aA[2], aB[2];
  #pragma unroll
  for (int na = 0; na < 2; ++na) bA[na] = *(const bf16x8*)(Bgl + (na << 9));
  #pragma unroll
  for (int ma = 0; ma < 2; ++ma) aA[ma] = *(const bf16x8*)(Agl + (ma << 14));

  f32x16 acc[2][2];
  #pragma unroll
  for (int i = 0; i < 2; ++i)
    #pragma unroll
    for (int j = 0; j < 2; ++j)
      #pragma unroll
      for (int e = 0; e < 16; ++e) acc[i][j][e] = 0.f;

  // one K16-step: prefetch A/B(kt+1) into nxt (4x contiguous 1 KiB), 4 MFMA on cur
  auto step = [&](int kt, bf16x8 (&curB)[2], bf16x8 (&nxtB)[2],
                  bf16x8 (&curA)[2], bf16x8 (&nxtA)[2]) {
    const int ktn = kt < 31 ? kt + 1 : 31;   // last iter: harmless dup reload
    #pragma unroll
    for (int na = 0; na < 2; ++na)
      nxtB[na] = *(const bf16x8*)(Bgl + (ktn << 13) + (na << 9));
    #pragma unroll
    for (int ma = 0; ma < 2; ++ma)
      nxtA[ma] = *(const bf16x8*)(Agl + (ma << 14) + (ktn << 9));
    #pragma unroll
    for (int ma = 0; ma < 2; ++ma)
      #pragma unroll
      for (int na = 0; na < 2; ++na)
        acc[ma][na] = __builtin_amdgcn_mfma_f32_32x32x16_bf16(
            curB[na], curA[ma], acc[ma][na], 0, 0, 0);
  };

  #pragma unroll
  for (int kt = 0; kt < 32; kt += 2) {   // static ping-pong (rule #20)
    step(kt,     bA, bB, aA, aB);
    step(kt + 1, bB, bA, aB, aA);
  }

  // ---- epilogue (r12, verified): 2 rounds (ma), region [32][516] f32.
  // C mapping (swapped operands): m = l31, n = (reg&3) + 4*hi + 8*(reg>>2).
  float (*epi)[516] = (float (*)[516])lds;
  fvec4 bvv[2][4];
  #pragma unroll
  for (int na = 0; na < 2; ++na)
    #pragma unroll
    for (int q = 0; q < 4; ++q)
      bvv[na][q] = *(const fvec4*)&bout[cb0 + (wid << 6) + (na << 5) +
                                       (q << 3) + (hi << 2)];

  #pragma unroll
  for (int ma = 0; ma < 2; ++ma) {
    asm volatile("s_waitcnt lgkmcnt(0)" ::: "memory");
    __builtin_amdgcn_s_barrier();   // prev round reads done
    #pragma unroll
    for (int na = 0; na < 2; ++na)
      #pragma unroll
      for (int q = 0; q < 4; ++q) {
        fvec4 o;
        #pragma unroll
        for (int j = 0; j < 4; ++j) o[j] = acc[ma][na][(q << 2) + j] + bvv[na][q][j];
        *(fvec4*)&epi[l31][(wid << 6) + (na << 5) + (q << 3) + (hi << 2)] = o;
      }
    asm volatile("s_waitcnt lgkmcnt(0)" ::: "memory");
    __builtin_amdgcn_s_barrier();   // deposits visible
    #pragma unroll
    for (int j = 0; j < 8; ++j) {
      const int idx = (wid << 3) + j;            // 0..63
      const int row = idx >> 1, seg = idx & 1;   // 32 rows x 2 segs
      fvec4 v = *(const fvec4*)&epi[row][(seg << 8) + (lane << 2)];
      const int gm = m0 + (ma << 5) + row;
      __builtin_nontemporal_store(
          v, (fvec4*)&out[(size_t)gm * 1024 + cb0 + (seg << 8) + (lane << 2)]);
    }
  }
}

extern "C" void kernel_launch(void* const* d_in, const int* in_sizes, int n_in,
                              void* d_out, int out_size, void* d_ws, size_t ws_size,
                              hipStream_t stream) {
  const float* enc   = (const float*)d_in[0];
  const float* pred  = (const float*)d_in[1];
  const float* W_enc = (const float*)d_in[2];
  const float* b_enc = (const float*)d_in[3];
  const float* W_dec = (const float*)d_in[4];
  const float* b_dec = (const float*)d_in[5];
  const float* W_out = (const float*)d_in[6];
  const float* b_out = (const float*)d_in[7];
  float* out = (float*)d_out;

  uint8_t* ws = (uint8_t*)d_ws;
  float* encp  = (float*)ws;                            // [1024][512] f32, 2 MiB
  float* predp = (float*)(ws + 2097152);                // [256][512]  f32, 0.5 MiB
  unsigned short* bt3 = (unsigned short*)(ws + 2621440);// K16-sliced W_out^T bf16, 1 MiB
  unsigned short* aj  = (unsigned short*)(ws + 3670016);// K16-sliced joint bf16, 64 MiB

  prep_kernel<<<288, 256, 0, stream>>>(enc, W_enc, b_enc, encp,
                                       pred, W_dec, b_dec, predp,
                                       W_out, bt3);
  joint_kernel<<<8192, 256, 0, stream>>>(encp, predp, aj);
  gemm_kernel<<<2048, 512, 0, stream>>>(aj, bt3, b_out, out);
}